// Round 3
// baseline (269.034 us; speedup 1.0000x reference)
//
#include <hip/hip_runtime.h>
#include <hip/hip_bf16.h>

typedef __bf16 bf16;
typedef bf16 bf16x8 __attribute__((ext_vector_type(8)));
typedef bf16 bf16x4 __attribute__((ext_vector_type(4)));
typedef float f32x4 __attribute__((ext_vector_type(4)));

#define BAR()   asm volatile("s_barrier" ::: "memory")
#define LGKM0() asm volatile("s_waitcnt lgkmcnt(0)" ::: "memory")
#define VMW(n)  asm volatile("s_waitcnt vmcnt(" #n ")" ::: "memory")

__device__ __forceinline__ void gload_lds16(const void* g, void* l) {
    __builtin_amdgcn_global_load_lds(
        (const __attribute__((address_space(1))) void*)g,
        (__attribute__((address_space(3))) void*)l, 16, 0, 0);
}

// ---------------------------------------------------------------------------
// 256x256 8-wave pipelined NT-GEMM core.  K processed in 32-wide slots on a
// 4-slot LDS ring (slot = A[256][32] + B[256][32] = 32KB; ring = 128KB).
// Per phase: stage slot s+3 (4x global_load_lds), counted vmcnt (slot s
// landed, s+1..s+3 in flight), barrier, 12x swizzled ds_read_b128, 32 MFMA.
// Source-side XOR swizzle (chunk ^= row&3) <-> same XOR on reads (rule 21).
// ---------------------------------------------------------------------------
__device__ __forceinline__
void gemm_core(const bf16* __restrict__ A0, const bf16* __restrict__ B0,
               const int ldA, const int ldB, const int nslots,
               char* smem, f32x4 (&acc)[8][4])
{
    const int t    = threadIdx.x;
    const int lane = t & 63;
    const int wid  = t >> 6;               // 0..7
    const int wr   = (wid >> 2) * 128;     // 2 M-waves
    const int wc   = (wid & 3) * 64;       // 4 N-waves
    const int rl   = lane & 15;
    const int koff = (((lane >> 4) ^ (rl & 3)) * 16);   // swizzled 16B chunk

    // Staging map: chunk c = j*512 + t -> row = j*128 + (t>>2), chunkcol = t&3.
    const int srow = t >> 2;                            // 0..127
    const int gk   = (((t & 3) ^ (srow & 3)) * 8);      // inverse-swizzled src k
    const bf16* pA0 = A0 + (long long)srow * ldA + gk;
    const bf16* pA1 = pA0 + (long long)128 * ldA;
    const bf16* pB0 = B0 + (long long)srow * ldB + gk;
    const bf16* pB1 = pB0 + (long long)128 * ldB;
    char* db0 = smem + (t & ~63) * 16;                  // wave-uniform + HW lane*16

#define STAGE(s_) { char* db = db0 + ((s_) & 3) * 32768; const int ko = (s_) * 32; \
    gload_lds16(pA0 + ko, db);         gload_lds16(pA1 + ko, db + 8192);           \
    gload_lds16(pB0 + ko, db + 16384); gload_lds16(pB1 + ko, db + 24576); }

    STAGE(0); STAGE(1); STAGE(2);

    for (int s = 0; s < nslots; ++s) {
        if (s + 3 < nslots) STAGE(s + 3);
        const int fut = nslots - 1 - s;
        if (fut >= 3)      VMW(12);
        else if (fut == 2) VMW(8);
        else if (fut == 1) VMW(4);
        else               VMW(0);
        BAR();
        const char* sa = smem + (s & 3) * 32768;
        const char* sb = sa + 16384;
        bf16x8 af[8], bfr[4];
#pragma unroll
        for (int m = 0; m < 8; ++m)
            af[m] = *(const bf16x8*)(sa + (wr + m * 16 + rl) * 64 + koff);
#pragma unroll
        for (int n = 0; n < 4; ++n)
            bfr[n] = *(const bf16x8*)(sb + (wc + n * 16 + rl) * 64 + koff);
        __builtin_amdgcn_s_setprio(1);
#pragma unroll
        for (int m = 0; m < 8; ++m)
#pragma unroll
            for (int n = 0; n < 4; ++n)
                acc[m][n] = __builtin_amdgcn_mfma_f32_16x16x32_bf16(
                                af[m], bfr[n], acc[m][n], 0, 0, 0);
        __builtin_amdgcn_s_setprio(0);
        LGKM0();   // reads complete before any wave's next-phase staging overwrites
        BAR();
    }
#undef STAGE
}

// ---------------------------------------------------------------------------
// Merged QKV projection: grid (12, 32).  bx -> {matrix, ncol}, by -> 256 rows.
// ---------------------------------------------------------------------------
__global__ __launch_bounds__(512, 2)
void gemm_qkv(const bf16* __restrict__ Xq, const bf16* __restrict__ Xk,
              const bf16* __restrict__ Xv,
              const bf16* __restrict__ WtQ, const bf16* __restrict__ WtK,
              const bf16* __restrict__ WtV,
              float* __restrict__ outQ, bf16* __restrict__ Qb,
              bf16* __restrict__ Kb, bf16* __restrict__ Vt)
{
    extern __shared__ char smem[];
    const int mat = blockIdx.x >> 2, nc = blockIdx.x & 3, by = blockIdx.y;
    const bf16* A = (mat == 0 ? Xq : mat == 1 ? Xk : Xv) + (long long)by * 256 * 1024;
    const bf16* B = (mat == 0 ? WtQ : mat == 1 ? WtK : WtV) + (long long)nc * 256 * 1024;
    f32x4 acc[8][4] = {};
    gemm_core(A, B, 1024, 1024, 32, smem, acc);

    const int t = threadIdx.x, lane = t & 63, wid = t >> 6;
    const int wr = (wid >> 2) * 128, wc = (wid & 3) * 64;
    const int rl = lane & 15, rg4 = (lane >> 4) * 4;
#pragma unroll
    for (int m = 0; m < 8; ++m)
#pragma unroll
        for (int n = 0; n < 4; ++n)
#pragma unroll
            for (int j = 0; j < 4; ++j) {
                const int row = by * 256 + wr + m * 16 + rg4 + j;
                const int col = nc * 256 + wc + n * 16 + rl;
                const float v = acc[m][n][j];
                if (mat == 0) { outQ[(long long)row * 1024 + col] = v;
                                Qb[(long long)row * 1024 + col] = (bf16)v; }
                else if (mat == 1) Kb[(long long)row * 1024 + col] = (bf16)v;
                else Vt[(long long)col * 8192 + row] = (bf16)v;
            }
}

// ---------------------------------------------------------------------------
// QK^T, causal 256-tiles: grid (8, 8, 4), skip bx > by.  Scaled f32 scores.
// ---------------------------------------------------------------------------
__global__ __launch_bounds__(512, 2)
void gemm_sc(const bf16* __restrict__ Qb, const bf16* __restrict__ Kb,
             float* __restrict__ scores, float scale)
{
    if (blockIdx.x > blockIdx.y) return;
    extern __shared__ char smem[];
    const int bx = blockIdx.x, by = blockIdx.y, bz = blockIdx.z;
    const long long boff = (long long)bz * 2048 * 1024;
    const bf16* A = Qb + boff + (long long)by * 256 * 1024;
    const bf16* B = Kb + boff + (long long)bx * 256 * 1024;
    f32x4 acc[8][4] = {};
    gemm_core(A, B, 1024, 1024, 32, smem, acc);

    const int t = threadIdx.x, lane = t & 63, wid = t >> 6;
    const int wr = (wid >> 2) * 128, wc = (wid & 3) * 64;
    const int rl = lane & 15, rg4 = (lane >> 4) * 4;
    float* Cb = scores + (long long)bz * 2048 * 2048;
#pragma unroll
    for (int m = 0; m < 8; ++m)
#pragma unroll
        for (int n = 0; n < 4; ++n)
#pragma unroll
            for (int j = 0; j < 4; ++j) {
                const int row = by * 256 + wr + m * 16 + rg4 + j;
                const int col = bx * 256 + wc + n * 16 + rl;
                Cb[(long long)row * 2048 + col] = acc[m][n][j] * scale;
            }
}

// ---------------------------------------------------------------------------
// PV: grid (4, 8, 4).  A = P (bf16 rows, ld 4096), B = Vt, K-limit (by+1)*256.
// ---------------------------------------------------------------------------
__global__ __launch_bounds__(512, 2)
void gemm_pv(const bf16* __restrict__ P, const bf16* __restrict__ Vt,
             float* __restrict__ outA)
{
    extern __shared__ char smem[];
    const int bx = blockIdx.x, by = blockIdx.y, bz = blockIdx.z;
    const bf16* A = P + (long long)bz * 2048 * 4096 + (long long)by * 256 * 4096;
    const bf16* B = Vt + (long long)bx * 256 * 8192 + (long long)bz * 2048;
    const int nslots = (by + 1) * 8;
    f32x4 acc[8][4] = {};
    gemm_core(A, B, 4096, 8192, nslots, smem, acc);

    const int t = threadIdx.x, lane = t & 63, wid = t >> 6;
    const int wr = (wid >> 2) * 128, wc = (wid & 3) * 64;
    const int rl = lane & 15, rg4 = (lane >> 4) * 4;
    float* Cb = outA + (long long)bz * 2048 * 1024;
#pragma unroll
    for (int m = 0; m < 8; ++m)
#pragma unroll
        for (int n = 0; n < 4; ++n)
#pragma unroll
            for (int j = 0; j < 4; ++j) {
                const int row = by * 256 + wr + m * 16 + rg4 + j;
                const int col = bx * 256 + wc + n * 16 + rl;
                Cb[(long long)row * 1024 + col] = acc[m][n][j];
            }
}

// ---------------------------------------------------------------------------
// f32 -> bf16 convert for the three X inputs.
// ---------------------------------------------------------------------------
__global__ __launch_bounds__(256)
void convert_x(const float* __restrict__ X0, const float* __restrict__ X1,
               const float* __restrict__ X2,
               bf16* __restrict__ Y0, bf16* __restrict__ Y1, bf16* __restrict__ Y2)
{
    const int which = blockIdx.x >> 12;
    const long long base = (((long long)(blockIdx.x & 4095)) * 256 + threadIdx.x) * 8;
    const float* X = which == 0 ? X0 : which == 1 ? X1 : X2;
    bf16*       Y = which == 0 ? Y0 : which == 1 ? Y1 : Y2;
    float4 a = *(const float4*)(X + base);
    float4 b = *(const float4*)(X + base + 4);
    bf16x8 v;
    v[0] = (bf16)a.x; v[1] = (bf16)a.y; v[2] = (bf16)a.z; v[3] = (bf16)a.w;
    v[4] = (bf16)b.x; v[5] = (bf16)b.y; v[6] = (bf16)b.z; v[7] = (bf16)b.w;
    *(bf16x8*)(Y + base) = v;
}

// ---------------------------------------------------------------------------
// Transpose-convert: Wt[n][k] = (bf16) W[k][n].
// ---------------------------------------------------------------------------
__global__ __launch_bounds__(256)
void transpose_w(const float* __restrict__ W, bf16* __restrict__ Wt) {
    __shared__ float tile[32][33];
    const int bx = blockIdx.x * 32;
    const int by = blockIdx.y * 32;
    const int tx = threadIdx.x;
    const int ty = threadIdx.y;
    for (int i = ty; i < 32; i += 8)
        tile[i][tx] = W[(size_t)(by + i) * 1024 + bx + tx];
    __syncthreads();
    for (int i = ty; i < 32; i += 8)
        Wt[(size_t)(bx + i) * 1024 + by + tx] = (bf16)tile[tx][i];
}

// ---------------------------------------------------------------------------
// Causal row softmax, in place f32 -> bf16.  Zero-fill extends to the
// enclosing 256-boundary so PV's 256-row tiles read only defined P.
// ---------------------------------------------------------------------------
__global__ __launch_bounds__(256)
void softmax_causal(float* __restrict__ scores)
{
    __shared__ float buf[2048];
    __shared__ float red[8];
    const int row = blockIdx.x;           // b*2048 + q
    const int q   = row & 2047;
    float* srow = scores + (size_t)row * 2048;
    bf16*  prow = (bf16*)srow;
    const int L = q + 1;
    const int tileEnd = ((q >> 8) + 1) << 8;   // 256-aligned, >= L
    const int t = threadIdx.x;
    const int lane = t & 63, wv = t >> 6;

    float m = -INFINITY;
    for (int k = t * 4; k < tileEnd; k += 1024) {
        float4 v = *(const float4*)(srow + k);
        float4 w;
        w.x = (k + 0 < L) ? v.x : -INFINITY;
        w.y = (k + 1 < L) ? v.y : -INFINITY;
        w.z = (k + 2 < L) ? v.z : -INFINITY;
        w.w = (k + 3 < L) ? v.w : -INFINITY;
        *(float4*)(buf + k) = w;
        m = fmaxf(fmaxf(fmaxf(m, w.x), w.y), fmaxf(w.z, w.w));
    }
#pragma unroll
    for (int o = 32; o; o >>= 1) m = fmaxf(m, __shfl_xor(m, o));
    if (lane == 0) red[wv] = m;
    __syncthreads();
    m = fmaxf(fmaxf(red[0], red[1]), fmaxf(red[2], red[3]));

    float s = 0.f;
    for (int k = t * 4; k < tileEnd; k += 1024) {
        float4 v = *(float4*)(buf + k);
        float4 e;
        e.x = __expf(v.x - m); e.y = __expf(v.y - m);
        e.z = __expf(v.z - m); e.w = __expf(v.w - m);
        s += (e.x + e.y) + (e.z + e.w);
        *(float4*)(buf + k) = e;
    }
#pragma unroll
    for (int o = 32; o; o >>= 1) s += __shfl_xor(s, o);
    if (lane == 0) red[4 + wv] = s;
    __syncthreads();
    s = (red[4] + red[5]) + (red[6] + red[7]);
    const float inv = 1.f / s;

    for (int k = t * 4; k < tileEnd; k += 1024) {
        float4 v = *(float4*)(buf + k);
        bf16x4 o;
        o[0] = (bf16)(v.x * inv); o[1] = (bf16)(v.y * inv);
        o[2] = (bf16)(v.z * inv); o[3] = (bf16)(v.w * inv);
        *(bf16x4*)(prow + k) = o;
    }
}

// ---------------------------------------------------------------------------
// Launch
// ---------------------------------------------------------------------------
extern "C" void kernel_launch(void* const* d_in, const int* in_sizes, int n_in,
                              void* d_out, int out_size, void* d_ws, size_t ws_size,
                              hipStream_t stream)
{
    const float* Xk = (const float*)d_in[0];
    const float* Xv = (const float*)d_in[1];
    const float* Xq = (const float*)d_in[2];
    const float* WK = (const float*)d_in[3];
    const float* WV = (const float*)d_in[4];
    const float* WQ = (const float*)d_in[5];

    float* outQ = (float*)d_out;                       // [4,2048,1024] f32
    float* outA = outQ + (size_t)8192 * 1024;          // [4,2048,1024] f32

    char* ws = (char*)d_ws;
    bf16*  Qb     = (bf16*)(ws);                       // 16MB
    bf16*  Kb     = (bf16*)(ws + (16ull << 20));       // 16MB
    bf16*  Vt     = (bf16*)(ws + (32ull << 20));       // 16MB  [1024][8192]
    float* scores = (float*)(ws + (48ull << 20));      // 64MB  [4][2048][2048]
    bf16*  Xqb    = (bf16*)(ws + (48ull << 20));       // aliases scores (dead after QK)
    bf16*  Xkb    = Xqb + (size_t)8 * 1024 * 1024;
    bf16*  Xvb    = Xkb + (size_t)8 * 1024 * 1024;
    bf16*  WtQ    = Xvb + (size_t)8 * 1024 * 1024;
    bf16*  WtK    = WtQ + (size_t)1024 * 1024;
    bf16*  WtV    = WtK + (size_t)1024 * 1024;

    const float scale = 0.022097086912079608f;         // 1/sqrt(2048)

    hipFuncSetAttribute((const void*)gemm_qkv, hipFuncAttributeMaxDynamicSharedMemorySize, 131072);
    hipFuncSetAttribute((const void*)gemm_sc,  hipFuncAttributeMaxDynamicSharedMemorySize, 131072);
    hipFuncSetAttribute((const void*)gemm_pv,  hipFuncAttributeMaxDynamicSharedMemorySize, 131072);

    convert_x<<<dim3(12288), 256, 0, stream>>>(Xq, Xk, Xv, Xqb, Xkb, Xvb);

    dim3 tb(32, 8);
    transpose_w<<<dim3(32, 32), tb, 0, stream>>>(WQ, WtQ);
    transpose_w<<<dim3(32, 32), tb, 0, stream>>>(WK, WtK);
    transpose_w<<<dim3(32, 32), tb, 0, stream>>>(WV, WtV);

    gemm_qkv<<<dim3(12, 32), 512, 131072, stream>>>(
        Xqb, Xkb, Xvb, WtQ, WtK, WtV, outQ, Qb, Kb, Vt);

    gemm_sc<<<dim3(8, 8, 4), 512, 131072, stream>>>(Qb, Kb, scores, scale);

    softmax_causal<<<dim3(8192), 256, 0, stream>>>(scores);

    gemm_pv<<<dim3(4, 8, 4), 512, 131072, stream>>>((const bf16*)scores, Vt, outA);
}

// Round 4
// 209.058 us; speedup vs baseline: 1.2869x; 1.2869x over previous
//
#include <hip/hip_runtime.h>
#include <hip/hip_bf16.h>

typedef __bf16 bf16;
typedef bf16 bf16x8 __attribute__((ext_vector_type(8)));
typedef bf16 bf16x4 __attribute__((ext_vector_type(4)));
typedef float f32x4 __attribute__((ext_vector_type(4)));

#define BAR()   asm volatile("s_barrier" ::: "memory")
#define LGKM0() asm volatile("s_waitcnt lgkmcnt(0)" ::: "memory")

__device__ __forceinline__ void gload_lds16(const void* g, void* l) {
    __builtin_amdgcn_global_load_lds(
        (const __attribute__((address_space(1))) void*)g,
        (__attribute__((address_space(3))) void*)l, 16, 0, 0);
}

// ---------------------------------------------------------------------------
// 128x128 NT-GEMM core, BK=64, double-buffered 64KB LDS (2 blocks/CU),
// counted vmcnt(8) pipeline, 3-bit XOR chunk swizzle (conflict-free b128).
// LDS layout per buffer: A[128][64] @0, B[128][64] @16KB; buffers at 0/32KB.
// Swizzle: LDS chunk-col cc (16B units) holds global chunk cc ^ (row&7);
// applied on the global SOURCE of global_load_lds (dest stays linear) and
// re-applied on ds_read addresses (rule 21).
// Waves: 2x2 of 64x64; per K-tile per wave: 16 ds_read_b128 + 32 MFMA,
// ONE barrier-pair, vmcnt never 0 except the last tile.
// ---------------------------------------------------------------------------
__device__ __forceinline__
void gemm_core128(const bf16* __restrict__ A0, const bf16* __restrict__ B0,
                  const int ldA, const int ldB, const int NT,
                  char* smem, f32x4 (&acc)[4][4])
{
    const int t    = threadIdx.x;
    const int lane = t & 63;
    const int wid  = t >> 6;
    const int wr   = (wid >> 1) * 64;
    const int wc   = (wid & 1) * 64;
    const int rl   = lane & 15;
    const int hi   = lane >> 4;        // 0..3
    const int r7   = lane & 7;

    // Staging map: load i stages chunk c = i*256+t -> row i*32+(t>>3), col t&7.
    const int tr = t >> 3;                          // 0..31
    const int gc = (t & 7) ^ (tr & 7);              // inverse-swizzled src chunk
    const bf16* pA = A0 + (long long)tr * ldA + gc * 8;
    const bf16* pB = B0 + (long long)tr * ldB + gc * 8;
    char* stBase = smem + (t & ~63) * 16;           // wave-uniform (+HW lane*16)

#define STAGE128(tt) { \
    char* db = stBase + ((tt) & 1) * 32768; \
    const bf16* a_ = pA + (tt) * 64; \
    const bf16* b_ = pB + (tt) * 64; \
    gload_lds16(a_,              db); \
    gload_lds16(a_ + 32ll * ldA, db + 4096); \
    gload_lds16(a_ + 64ll * ldA, db + 8192); \
    gload_lds16(a_ + 96ll * ldA, db + 12288); \
    gload_lds16(b_,              db + 16384); \
    gload_lds16(b_ + 32ll * ldB, db + 20480); \
    gload_lds16(b_ + 64ll * ldB, db + 24576); \
    gload_lds16(b_ + 96ll * ldB, db + 28672); }

    STAGE128(0);
    for (int tt = 0; tt < NT; ++tt) {
        if (tt + 1 < NT) {
            STAGE128(tt + 1);
            asm volatile("s_waitcnt vmcnt(8)" ::: "memory");  // tile tt landed
        } else {
            asm volatile("s_waitcnt vmcnt(0)" ::: "memory");
        }
        BAR();
        const char* ba = smem + (tt & 1) * 32768;
        const char* bb = ba + 16384;
#pragma unroll
        for (int ks = 0; ks < 2; ++ks) {
            bf16x8 af[4], bfr[4];
#pragma unroll
            for (int m = 0; m < 4; ++m) {
                const int r = wr + m * 16 + rl;
                af[m] = *(const bf16x8*)(ba + r * 128 + ((((ks << 2) | hi) ^ r7) << 4));
            }
#pragma unroll
            for (int n = 0; n < 4; ++n) {
                const int r = wc + n * 16 + rl;
                bfr[n] = *(const bf16x8*)(bb + r * 128 + ((((ks << 2) | hi) ^ r7) << 4));
            }
            __builtin_amdgcn_s_setprio(1);
#pragma unroll
            for (int m = 0; m < 4; ++m)
#pragma unroll
                for (int n = 0; n < 4; ++n)
                    acc[m][n] = __builtin_amdgcn_mfma_f32_16x16x32_bf16(
                                    af[m], bfr[n], acc[m][n], 0, 0, 0);
            __builtin_amdgcn_s_setprio(0);
        }
        LGKM0();      // all reads of buf[tt&1] done before next tile's staging
        BAR();
    }
#undef STAGE128
}

// ---------------------------------------------------------------------------
// Merged QKV projections: grid (24, 64).  bx = mat*8 + ncol, by = 128-row blk.
// ---------------------------------------------------------------------------
__global__ __launch_bounds__(256, 2)
void gemm_qkv(const bf16* __restrict__ Xq, const bf16* __restrict__ Xk,
              const bf16* __restrict__ Xv,
              const bf16* __restrict__ WtQ, const bf16* __restrict__ WtK,
              const bf16* __restrict__ WtV,
              float* __restrict__ outQ, bf16* __restrict__ Qb,
              bf16* __restrict__ Kb, bf16* __restrict__ Vt)
{
    extern __shared__ char smem[];
    const int mat = blockIdx.x >> 3, nc = blockIdx.x & 7, by = blockIdx.y;
    const bf16* A = (mat == 0 ? Xq : mat == 1 ? Xk : Xv) + (long long)by * 128 * 1024;
    const bf16* B = (mat == 0 ? WtQ : mat == 1 ? WtK : WtV) + (long long)nc * 128 * 1024;
    f32x4 acc[4][4] = {};
    gemm_core128(A, B, 1024, 1024, 16, smem, acc);

    const int t = threadIdx.x, lane = t & 63, wid = t >> 6;
    const int wr = (wid >> 1) * 64, wc = (wid & 1) * 64;
    const int rl = lane & 15, rg4 = (lane >> 4) * 4;
#pragma unroll
    for (int m = 0; m < 4; ++m)
#pragma unroll
        for (int n = 0; n < 4; ++n)
#pragma unroll
            for (int j = 0; j < 4; ++j) {
                const int row = by * 128 + wr + m * 16 + rg4 + j;
                const int col = nc * 128 + wc + n * 16 + rl;
                const float v = acc[m][n][j];
                if (mat == 0) { outQ[(long long)row * 1024 + col] = v;
                                Qb[(long long)row * 1024 + col] = (bf16)v; }
                else if (mat == 1) Kb[(long long)row * 1024 + col] = (bf16)v;
                else Vt[(long long)col * 8192 + row] = (bf16)v;
            }
}

// ---------------------------------------------------------------------------
// QK^T causal: grid (16, 16, 4), skip bx > by.  Scaled f32 scores.
// ---------------------------------------------------------------------------
__global__ __launch_bounds__(256, 2)
void gemm_sc(const bf16* __restrict__ Qb, const bf16* __restrict__ Kb,
             float* __restrict__ scores, float scale)
{
    if (blockIdx.x > blockIdx.y) return;
    extern __shared__ char smem[];
    const int bx = blockIdx.x, by = blockIdx.y, bz = blockIdx.z;
    const long long boff = (long long)bz * 2048 * 1024;
    f32x4 acc[4][4] = {};
    gemm_core128(Qb + boff + (long long)by * 128 * 1024,
                 Kb + boff + (long long)bx * 128 * 1024, 1024, 1024, 16, smem, acc);

    const int t = threadIdx.x, lane = t & 63, wid = t >> 6;
    const int wr = (wid >> 1) * 64, wc = (wid & 1) * 64;
    const int rl = lane & 15, rg4 = (lane >> 4) * 4;
    float* Cb = scores + (long long)bz * 2048 * 2048;
#pragma unroll
    for (int m = 0; m < 4; ++m)
#pragma unroll
        for (int n = 0; n < 4; ++n)
#pragma unroll
            for (int j = 0; j < 4; ++j) {
                const int row = by * 128 + wr + m * 16 + rg4 + j;
                const int col = bx * 128 + wc + n * 16 + rl;
                Cb[(long long)row * 2048 + col] = acc[m][n][j] * scale;
            }
}

// ---------------------------------------------------------------------------
// PV: grid (8, 16, 4).  A = P (bf16, ld 4096), B = Vt (ld 8192),
// K-limit (by+1)*128 -> NT = (by+1)*2.
// ---------------------------------------------------------------------------
__global__ __launch_bounds__(256, 2)
void gemm_pv(const bf16* __restrict__ P, const bf16* __restrict__ Vt,
             float* __restrict__ outA)
{
    extern __shared__ char smem[];
    const int bx = blockIdx.x, by = blockIdx.y, bz = blockIdx.z;
    f32x4 acc[4][4] = {};
    gemm_core128(P + (long long)bz * 2048 * 4096 + (long long)by * 128 * 4096,
                 Vt + (long long)bx * 128 * 8192 + (long long)bz * 2048,
                 4096, 8192, (by + 1) * 2, smem, acc);

    const int t = threadIdx.x, lane = t & 63, wid = t >> 6;
    const int wr = (wid >> 1) * 64, wc = (wid & 1) * 64;
    const int rl = lane & 15, rg4 = (lane >> 4) * 4;
    float* Cb = outA + (long long)bz * 2048 * 1024;
#pragma unroll
    for (int m = 0; m < 4; ++m)
#pragma unroll
        for (int n = 0; n < 4; ++n)
#pragma unroll
            for (int j = 0; j < 4; ++j) {
                const int row = by * 128 + wr + m * 16 + rg4 + j;
                const int col = bx * 128 + wc + n * 16 + rl;
                Cb[(long long)row * 1024 + col] = acc[m][n][j];
            }
}

// ---------------------------------------------------------------------------
// f32 -> bf16 convert for the three X inputs.
// ---------------------------------------------------------------------------
__global__ __launch_bounds__(256)
void convert_x(const float* __restrict__ X0, const float* __restrict__ X1,
               const float* __restrict__ X2,
               bf16* __restrict__ Y0, bf16* __restrict__ Y1, bf16* __restrict__ Y2)
{
    const int which = blockIdx.x >> 12;
    const long long base = (((long long)(blockIdx.x & 4095)) * 256 + threadIdx.x) * 8;
    const float* X = which == 0 ? X0 : which == 1 ? X1 : X2;
    bf16*       Y = which == 0 ? Y0 : which == 1 ? Y1 : Y2;
    float4 a = *(const float4*)(X + base);
    float4 b = *(const float4*)(X + base + 4);
    bf16x8 v;
    v[0] = (bf16)a.x; v[1] = (bf16)a.y; v[2] = (bf16)a.z; v[3] = (bf16)a.w;
    v[4] = (bf16)b.x; v[5] = (bf16)b.y; v[6] = (bf16)b.z; v[7] = (bf16)b.w;
    *(bf16x8*)(Y + base) = v;
}

// ---------------------------------------------------------------------------
// Transpose-convert: Wt[n][k] = (bf16) W[k][n].
// ---------------------------------------------------------------------------
__global__ __launch_bounds__(256)
void transpose_w(const float* __restrict__ W, bf16* __restrict__ Wt) {
    __shared__ float tile[32][33];
    const int bx = blockIdx.x * 32;
    const int by = blockIdx.y * 32;
    const int tx = threadIdx.x;
    const int ty = threadIdx.y;
    for (int i = ty; i < 32; i += 8)
        tile[i][tx] = W[(size_t)(by + i) * 1024 + bx + tx];
    __syncthreads();
    for (int i = ty; i < 32; i += 8)
        Wt[(size_t)(bx + i) * 1024 + by + tx] = (bf16)tile[tx][i];
}

// ---------------------------------------------------------------------------
// Causal row softmax, in place f32 -> bf16 (zero-fill to 256-boundary).
// ---------------------------------------------------------------------------
__global__ __launch_bounds__(256)
void softmax_causal(float* __restrict__ scores)
{
    __shared__ float buf[2048];
    __shared__ float red[8];
    const int row = blockIdx.x;           // b*2048 + q
    const int q   = row & 2047;
    float* srow = scores + (size_t)row * 2048;
    bf16*  prow = (bf16*)srow;
    const int L = q + 1;
    const int tileEnd = ((q >> 8) + 1) << 8;
    const int t = threadIdx.x;
    const int lane = t & 63, wv = t >> 6;

    float m = -INFINITY;
    for (int k = t * 4; k < tileEnd; k += 1024) {
        float4 v = *(const float4*)(srow + k);
        float4 w;
        w.x = (k + 0 < L) ? v.x : -INFINITY;
        w.y = (k + 1 < L) ? v.y : -INFINITY;
        w.z = (k + 2 < L) ? v.z : -INFINITY;
        w.w = (k + 3 < L) ? v.w : -INFINITY;
        *(float4*)(buf + k) = w;
        m = fmaxf(fmaxf(fmaxf(m, w.x), w.y), fmaxf(w.z, w.w));
    }
#pragma unroll
    for (int o = 32; o; o >>= 1) m = fmaxf(m, __shfl_xor(m, o));
    if (lane == 0) red[wv] = m;
    __syncthreads();
    m = fmaxf(fmaxf(red[0], red[1]), fmaxf(red[2], red[3]));

    float s = 0.f;
    for (int k = t * 4; k < tileEnd; k += 1024) {
        float4 v = *(float4*)(buf + k);
        float4 e;
        e.x = __expf(v.x - m); e.y = __expf(v.y - m);
        e.z = __expf(v.z - m); e.w = __expf(v.w - m);
        s += (e.x + e.y) + (e.z + e.w);
        *(float4*)(buf + k) = e;
    }
#pragma unroll
    for (int o = 32; o; o >>= 1) s += __shfl_xor(s, o);
    if (lane == 0) red[4 + wv] = s;
    __syncthreads();
    s = (red[4] + red[5]) + (red[6] + red[7]);
    const float inv = 1.f / s;

    for (int k = t * 4; k < tileEnd; k += 1024) {
        float4 v = *(float4*)(buf + k);
        bf16x4 o;
        o[0] = (bf16)(v.x * inv); o[1] = (bf16)(v.y * inv);
        o[2] = (bf16)(v.z * inv); o[3] = (bf16)(v.w * inv);
        *(bf16x4*)(prow + k) = o;
    }
}

// ---------------------------------------------------------------------------
// Launch
// ---------------------------------------------------------------------------
extern "C" void kernel_launch(void* const* d_in, const int* in_sizes, int n_in,
                              void* d_out, int out_size, void* d_ws, size_t ws_size,
                              hipStream_t stream)
{
    const float* Xk = (const float*)d_in[0];
    const float* Xv = (const float*)d_in[1];
    const float* Xq = (const float*)d_in[2];
    const float* WK = (const float*)d_in[3];
    const float* WV = (const float*)d_in[4];
    const float* WQ = (const float*)d_in[5];

    float* outQ = (float*)d_out;                       // [4,2048,1024] f32
    float* outA = outQ + (size_t)8192 * 1024;          // [4,2048,1024] f32

    char* ws = (char*)d_ws;
    bf16*  Qb     = (bf16*)(ws);                       // 16MB
    bf16*  Kb     = (bf16*)(ws + (16ull << 20));       // 16MB
    bf16*  Vt     = (bf16*)(ws + (32ull << 20));       // 16MB  [1024][8192]
    float* scores = (float*)(ws + (48ull << 20));      // 64MB  [4][2048][2048]
    bf16*  Xqb    = (bf16*)(ws + (48ull << 20));       // aliases scores
    bf16*  Xkb    = Xqb + (size_t)8 * 1024 * 1024;
    bf16*  Xvb    = Xkb + (size_t)8 * 1024 * 1024;
    bf16*  WtQ    = Xvb + (size_t)8 * 1024 * 1024;
    bf16*  WtK    = WtQ + (size_t)1024 * 1024;
    bf16*  WtV    = WtK + (size_t)1024 * 1024;

    const float scale = 0.022097086912079608f;         // 1/sqrt(2048)

    hipFuncSetAttribute((const void*)gemm_qkv, hipFuncAttributeMaxDynamicSharedMemorySize, 65536);
    hipFuncSetAttribute((const void*)gemm_sc,  hipFuncAttributeMaxDynamicSharedMemorySize, 65536);
    hipFuncSetAttribute((const void*)gemm_pv,  hipFuncAttributeMaxDynamicSharedMemorySize, 65536);

    convert_x<<<dim3(12288), 256, 0, stream>>>(Xq, Xk, Xv, Xqb, Xkb, Xvb);

    dim3 tb(32, 8);
    transpose_w<<<dim3(32, 32), tb, 0, stream>>>(WQ, WtQ);
    transpose_w<<<dim3(32, 32), tb, 0, stream>>>(WK, WtK);
    transpose_w<<<dim3(32, 32), tb, 0, stream>>>(WV, WtV);

    gemm_qkv<<<dim3(24, 64), 256, 65536, stream>>>(
        Xqb, Xkb, Xvb, WtQ, WtK, WtV, outQ, Qb, Kb, Vt);

    gemm_sc<<<dim3(16, 16, 4), 256, 65536, stream>>>(Qb, Kb, scores, scale);

    softmax_causal<<<dim3(8192), 256, 0, stream>>>(scores);

    gemm_pv<<<dim3(8, 16, 4), 256, 65536, stream>>>((const bf16*)scores, Vt, outA);
}